// Round 4
// baseline (2063.155 us; speedup 1.0000x reference)
//
#include <hip/hip_runtime.h>
#include <stdint.h>
#include <math.h>

// ---------------------------------------------------------------------------
// Swin block, MI355X. B=32 H=W=112 C=192 NH=6 hd=32 WS=7 SS=3 -> 8192 windows,
// 49 tokens, 401408 token-rows.
// R3: col-loop GEMM (gemm_cl): grid = row-blocks only; A staged once/block,
//     A-fragments register-cached, W tiles prefetched under compute (kills the
//     4x XCD A over-fetch). proj fuses residual + LN2 (ln_kern<false> gone).
//     fc2 k-staged with 3 live accumulators + token scatter-add epilogue.
// ---------------------------------------------------------------------------

typedef unsigned short u16;
typedef unsigned int   u32;
typedef __bf16 v8bf __attribute__((ext_vector_type(8)));
typedef float  v4f  __attribute__((ext_vector_type(4)));
typedef u16    v8u16 __attribute__((ext_vector_type(8)));
typedef u16    v4u16 __attribute__((ext_vector_type(4)));

#define MFMA16(a,b,c) __builtin_amdgcn_mfma_f32_16x16x32_bf16(a,b,c,0,0,0)

#define HSTR 77070336L          // elems per q/k/v array (8192*6*49*32)

__device__ __forceinline__ u16 f2bf(float f){
  u32 u = __builtin_bit_cast(u32, f);
  u32 r = u + 0x7FFFu + ((u >> 16) & 1u);   // RNE
  return (u16)(r >> 16);
}

__device__ __forceinline__ void async16(void* lds, const void* g){
  __builtin_amdgcn_global_load_lds(
      (__attribute__((address_space(1))) void*)(g),
      (__attribute__((address_space(3))) void*)(lds), 16, 0, 0);
}

// ------------------------------ weight convert -----------------------------
__global__ __launch_bounds__(256) void convk(const float* __restrict__ s,
                                             u16* __restrict__ d, int n){
  int i = blockIdx.x * 256 + threadIdx.x;
  if (i < n) d[i] = f2bf(s[i]);
}

// -------------------- fused rel-pos-bias + shift-mask table ----------------
// layout: [cls][h][m][n][lr][lg*4+r]  (matches MFMA C fragment, b128/lane)
__global__ __launch_bounds__(256)
void bmt_k(const float* __restrict__ rpb, float* __restrict__ bmt){
  int idx = blockIdx.x * 256 + threadIdx.x;      // 98304 total
  int r  = idx & 3, lg = (idx >> 2) & 3, lr = (idx >> 4) & 15;
  int n  = (idx >> 8) & 3, m = (idx >> 10) & 3;
  int t  = idx >> 12; int h = t % 6, cls = t / 6;
  int row = m*16 + lg*4 + r, col = n*16 + lr;
  float v;
  if (row >= 49 || col >= 49){
    v = -1e30f;
  } else {
    int i1 = row / 7, j1 = row - i1 * 7;
    int i2 = col / 7, j2 = col - i2 * 7;
    int ridx = (i1 - i2 + 6) * 13 + (j1 - j2 + 6);
    v = rpb[ridx * 6 + h];
    int lh1 = (cls & 2) ? (i1 < 4 ? 1 : 2) : 0;
    int lw1 = (cls & 1) ? (j1 < 4 ? 1 : 2) : 0;
    int lh2 = (cls & 2) ? (i2 < 4 ? 1 : 2) : 0;
    int lw2 = (cls & 1) ? (j2 < 4 ? 1 : 2) : 0;
    if (lh1 * 3 + lw1 != lh2 * 3 + lw2) v -= 100.f;
  }
  bmt[idx] = v;
}

// ----------------------- LayerNorm1 (gathered) -----------------------------
// 16 lanes per token, 4 tokens per wave; lane handles 12 channels (3 float4).
__global__ __launch_bounds__(256)
void ln_kern(const float* __restrict__ x, const float* __restrict__ g,
             const float* __restrict__ b, u16* __restrict__ o){
  const int ts  = threadIdx.x >> 4;
  const int l16 = threadIdx.x & 15;
  const int r   = blockIdx.x * 16 + ts;          // < 401408
  u32 wdx = (u32)r / 49u; int nn = r - (int)wdx * 49;
  int bb = (int)(wdx >> 8); int wl = (int)(wdx & 255);
  int wh = wl >> 4, wwi = wl & 15;
  int ii = (int)((u32)nn / 7u), jj = nn - ii * 7;
  int th = wh * 7 + ii + 3;  if (th >= 112) th -= 112;
  int tw = wwi * 7 + jj + 3; if (tw >= 112) tw -= 112;
  const float* src = x + (u32)(bb * 12544 + th * 112 + tw) * 192u;
  const float4 a0 = *(const float4*)(src + l16*12);
  const float4 a1 = *(const float4*)(src + l16*12 + 4);
  const float4 a2 = *(const float4*)(src + l16*12 + 8);
  float sm = ((a0.x+a0.y)+(a0.z+a0.w)) + ((a1.x+a1.y)+(a1.z+a1.w))
           + ((a2.x+a2.y)+(a2.z+a2.w));
  float sq = ((a0.x*a0.x+a0.y*a0.y)+(a0.z*a0.z+a0.w*a0.w))
           + ((a1.x*a1.x+a1.y*a1.y)+(a1.z*a1.z+a1.w*a1.w))
           + ((a2.x*a2.x+a2.y*a2.y)+(a2.z*a2.z+a2.w*a2.w));
  #pragma unroll
  for (int d = 1; d < 16; d <<= 1){
    sm += __shfl_xor(sm, d, 64);
    sq += __shfl_xor(sq, d, 64);
  }
  float mean = sm * (1.f/192.f);
  float var  = sq * (1.f/192.f) - mean * mean;
  float rs   = rsqrtf(var + 1e-5f);
  const float4 g0 = *(const float4*)(g + l16*12);
  const float4 g1 = *(const float4*)(g + l16*12 + 4);
  const float4 g2 = *(const float4*)(g + l16*12 + 8);
  const float4 b0 = *(const float4*)(b + l16*12);
  const float4 b1 = *(const float4*)(b + l16*12 + 4);
  const float4 b2 = *(const float4*)(b + l16*12 + 8);
  u16* dst = o + (u32)r * 192u + l16 * 12;
  v4u16 w0, w1, w2;
  w0[0]=f2bf((a0.x-mean)*rs*g0.x+b0.x); w0[1]=f2bf((a0.y-mean)*rs*g0.y+b0.y);
  w0[2]=f2bf((a0.z-mean)*rs*g0.z+b0.z); w0[3]=f2bf((a0.w-mean)*rs*g0.w+b0.w);
  w1[0]=f2bf((a1.x-mean)*rs*g1.x+b1.x); w1[1]=f2bf((a1.y-mean)*rs*g1.y+b1.y);
  w1[2]=f2bf((a1.z-mean)*rs*g1.z+b1.z); w1[3]=f2bf((a1.w-mean)*rs*g1.w+b1.w);
  w2[0]=f2bf((a2.x-mean)*rs*g2.x+b2.x); w2[1]=f2bf((a2.y-mean)*rs*g2.y+b2.y);
  w2[2]=f2bf((a2.z-mean)*rs*g2.z+b2.z); w2[3]=f2bf((a2.w-mean)*rs*g2.w+b2.w);
  *(v4u16*)(dst)     = w0;
  *(v4u16*)(dst + 4) = w1;
  *(v4u16*)(dst + 8) = w2;
}

// ------------------------- staging helpers (LDS rows padded to 200) --------
__device__ __forceinline__ void stageA128(u16* sA, const u16* __restrict__ A,
                                          u32 ld, u32 rowBase, u32 k0,
                                          int wv, int rA0, int cA0){
  int ra = rA0, ca = cA0;
  #pragma unroll
  for (int it = 0; it < 12; ++it){
    int cc = (ca == 24) ? 23 : ca;
    async16((char*)sA + (size_t)(it * 256 + wv * 64) * 16,
            A + (rowBase + (u32)ra) * ld + (k0 + (u32)cc * 8u));
    ra += 10; ca += 6; if (ca >= 25){ ca -= 25; ra += 1; }
  }
  if (wv < 2){
    int cc = (ca == 24) ? 23 : ca;
    async16((char*)sA + (size_t)(3072 + wv * 64) * 16,
            A + (rowBase + (u32)ra) * ld + (k0 + (u32)cc * 8u));
  }
}

__device__ __forceinline__ void stageW64(u16* sW, const u16* __restrict__ W,
                                         u32 ld, u32 rowBase, u32 k0,
                                         int wv, int rA0, int cA0){
  int rw = rA0, cw = cA0;
  #pragma unroll
  for (int it = 0; it < 6; ++it){
    int cc = (cw == 24) ? 23 : cw;
    async16((char*)sW + (size_t)(it * 256 + wv * 64) * 16,
            W + (rowBase + (u32)rw) * ld + (k0 + (u32)cc * 8u));
    rw += 10; cw += 6; if (cw >= 25){ cw -= 25; rw += 1; }
  }
  if (wv == 0){
    int cc = (cw == 24) ? 23 : cw;
    async16((char*)sW + (size_t)1536 * 16,
            W + (rowBase + (u32)rw) * ld + (k0 + (u32)cc * 8u));
  }
}

// ---------------------- col-loop GEMM (A @ W^T), BM=128 --------------------
// grid.x = row-blocks. Per block: stage A once, cache A-frags in regs, loop
// NT col-tiles (stage next W under current compute). EPI:
//   0 qkv (NT=9)  : scale-q + permuted q/k/v store, per-tile epilogue
//   1 proj (NT=3) : live acc; epilogue = +residual -> x1(fp32,d_out) + LN2
//                   -> xln2(bf16, in-place over A rows)
//   2 fc1 (NT=12) : gelu -> h1 bf16, per-tile epilogue
//   3 fc2 (NT=3, K=768 via 4 k-stages): live acc; token scatter-add epilogue
template<int EPI, int NT>
__global__ __launch_bounds__(256)
void gemm_cl(const u16* __restrict__ A, int ldA,
             const u16* __restrict__ W, int ldW,
             const float* __restrict__ bias,
             u16* __restrict__ ob, float* __restrict__ of,
             const float* __restrict__ xres,
             const float* __restrict__ lng, const float* __restrict__ lnb,
             int rowOff){
  constexpr int KS   = (EPI == 3) ? 4 : 1;
  constexpr bool LIVE = (EPI == 1 || EPI == 3);
  __shared__ __align__(16) u16 sA[128 * 200];
  __shared__ __align__(16) u16 sW[64 * 200];
  __shared__ float2 red[2][128];
  const int tid = threadIdx.x;
  const int wv = tid >> 6, lnn = tid & 63;
  const int lr = lnn & 15, lg = lnn >> 4;
  const int m0 = (int)blockIdx.x * 128;
  const int wr = wv >> 1, wc = wv & 1;
  const int rA0 = (int)((u32)tid / 25u);
  const int cA0 = tid - rA0 * 25;

  v4f acc[LIVE ? NT : 1][4][2];
  if (LIVE){
    #pragma unroll
    for (int t = 0; t < (LIVE ? NT : 1); ++t){
      float b0 = bias[t*64 + wc*32 + lr];
      float b1 = bias[t*64 + wc*32 + 16 + lr];
      #pragma unroll
      for (int m = 0; m < 4; ++m){
        acc[t][m][0] = (v4f){b0, b0, b0, b0};
        acc[t][m][1] = (v4f){b1, b1, b1, b1};
      }
    }
  }

  stageA128(sA, A, (u32)ldA, (u32)m0, 0, wv, rA0, cA0);
  stageW64 (sW, W, (u32)ldW, 0, 0, wv, rA0, cA0);
  __syncthreads();

  for (int ks = 0; ks < KS; ++ks){           // runtime loop (acc not ks-indexed)
    v8bf af[4][6];
    #pragma unroll
    for (int m = 0; m < 4; ++m)
      #pragma unroll
      for (int kk = 0; kk < 6; ++kk)
        af[m][kk] = *(const v8bf*)&sA[(wr*64 + m*16 + lr)*200 + kk*32 + lg*8];

    #pragma unroll
    for (int t = 0; t < NT; ++t){
      v8bf wf[2][6];
      #pragma unroll
      for (int n = 0; n < 2; ++n)
        #pragma unroll
        for (int kk = 0; kk < 6; ++kk)
          wf[n][kk] = *(const v8bf*)&sW[(wc*32 + n*16 + lr)*200 + kk*32 + lg*8];
      __syncthreads();                        // all wf reads done before restage
      if (t + 1 < NT){
        stageW64(sW, W, (u32)ldW, (u32)((t+1)*64), (u32)(ks*192), wv, rA0, cA0);
      } else if (ks + 1 < KS){
        stageA128(sA, A, (u32)ldA, (u32)m0, (u32)((ks+1)*192), wv, rA0, cA0);
        stageW64 (sW, W, (u32)ldW, 0, (u32)((ks+1)*192), wv, rA0, cA0);
      }

      if (LIVE){
        #pragma unroll
        for (int kk = 0; kk < 6; ++kk)
          #pragma unroll
          for (int m = 0; m < 4; ++m){
            acc[t][m][0] = MFMA16(af[m][kk], wf[0][kk], acc[t][m][0]);
            acc[t][m][1] = MFMA16(af[m][kk], wf[1][kk], acc[t][m][1]);
          }
      } else {
        float b0 = bias[t*64 + wc*32 + lr];
        float b1 = bias[t*64 + wc*32 + 16 + lr];
        v4f ac[4][2];
        #pragma unroll
        for (int m = 0; m < 4; ++m){
          ac[m][0] = (v4f){b0, b0, b0, b0};
          ac[m][1] = (v4f){b1, b1, b1, b1};
        }
        #pragma unroll
        for (int kk = 0; kk < 6; ++kk)
          #pragma unroll
          for (int m = 0; m < 4; ++m){
            ac[m][0] = MFMA16(af[m][kk], wf[0][kk], ac[m][0]);
            ac[m][1] = MFMA16(af[m][kk], wf[1][kk], ac[m][1]);
          }
        // per-tile epilogue.  D layout: row = 4*lg + r, col = lr
        #pragma unroll
        for (int m = 0; m < 4; ++m)
          #pragma unroll
          for (int n = 0; n < 2; ++n)
            #pragma unroll
            for (int r = 0; r < 4; ++r){
              const int lrow = m0 + wr*64 + m*16 + lg*4 + r;
              const int col  = t*64 + wc*32 + n*16 + lr;
              float val = ac[m][n][r];
              if (EPI == 0){
                int which = (col >= 384) ? 2 : ((col >= 192) ? 1 : 0);
                int rem = col - which * 192;
                int hh = rem >> 5, dd = rem & 31;
                if (which == 0) val *= 0.17677669529663687f;  // hd^-0.5
                u32 wdx = (u32)lrow / 49u; u32 nn2 = (u32)lrow - wdx * 49u;
                ob[(u32)which * 77070336u + ((wdx*6u + (u32)hh)*49u + nn2)*32u
                   + (u32)dd] = f2bf(val);
              } else {  // EPI == 2
                float gg = 0.5f * val * (1.0f + erff(val * 0.7071067811865475f));
                ob[(u32)lrow * 768u + (u32)col] = f2bf(gg);
              }
            }
      }
      __syncthreads();                        // drains staged W/A for next iter
    }
  }

  if (EPI == 1){
    // -------- residual add (in place into acc) + x1 store + LN stats -------
    float sm_[4][4], sq_[4][4];
    u32 adrb[4][4];
    #pragma unroll
    for (int m = 0; m < 4; ++m)
      #pragma unroll
      for (int r = 0; r < 4; ++r){
        const int gr = m0 + wr*64 + m*16 + lg*4 + r;
        u32 wdx = (u32)gr / 49u; int nn = gr - (int)wdx * 49;
        int bb = (int)(wdx >> 8); int wl = (int)(wdx & 255);
        int wh = wl >> 4, wwi = wl & 15;
        int ii = (int)((u32)nn / 7u), jj = nn - ii * 7;
        int th = wh * 7 + ii + 3;  if (th >= 112) th -= 112;
        int tw = wwi * 7 + jj + 3; if (tw >= 112) tw -= 112;
        u32 adr = (u32)(bb * 12544 + th * 112 + tw) * 192u;
        adrb[m][r] = adr;
        float sm = 0.f, sq = 0.f;
        #pragma unroll
        for (int t = 0; t < 3; ++t)
          #pragma unroll
          for (int n = 0; n < 2; ++n){
            const int col = t*64 + wc*32 + n*16 + lr;
            float v = acc[t][m][n][r] + xres[adr + (u32)col];
            acc[t][m][n][r] = v;
            of[adr + (u32)col] = v;            // x1 fp32 -> d_out
            sm += v; sq += v*v;
          }
        sm_[m][r] = sm; sq_[m][r] = sq;
      }
    #pragma unroll
    for (int d = 1; d < 16; d <<= 1)
      #pragma unroll
      for (int m = 0; m < 4; ++m)
        #pragma unroll
        for (int r = 0; r < 4; ++r){
          sm_[m][r] += __shfl_xor(sm_[m][r], d, 64);
          sq_[m][r] += __shfl_xor(sq_[m][r], d, 64);
        }
    if (lr == 0){
      #pragma unroll
      for (int m = 0; m < 4; ++m)
        #pragma unroll
        for (int r = 0; r < 4; ++r)
          red[wc][wr*64 + m*16 + lg*4 + r] = make_float2(sm_[m][r], sq_[m][r]);
    }
    __syncthreads();
    #pragma unroll
    for (int m = 0; m < 4; ++m)
      #pragma unroll
      for (int r = 0; r < 4; ++r){
        const int rl = wr*64 + m*16 + lg*4 + r;
        const int gr = m0 + rl;
        float2 c0 = red[0][rl], c1 = red[1][rl];
        float mean = (c0.x + c1.x) * (1.f/192.f);
        float var  = (c0.y + c1.y) * (1.f/192.f) - mean*mean;
        float rs   = rsqrtf(var + 1e-5f);
        #pragma unroll
        for (int t = 0; t < 3; ++t)
          #pragma unroll
          for (int n = 0; n < 2; ++n){
            const int col = t*64 + wc*32 + n*16 + lr;
            float v = (acc[t][m][n][r] - mean) * rs * lng[col] + lnb[col];
            ob[(u32)gr * 192u + (u32)col] = f2bf(v);   // xln2, in place
          }
      }
  }

  if (EPI == 3){
    // ----------------- token scatter-add epilogue (+= into d_out) ----------
    #pragma unroll
    for (int m = 0; m < 4; ++m)
      #pragma unroll
      for (int r = 0; r < 4; ++r){
        const int gr = rowOff + m0 + wr*64 + m*16 + lg*4 + r;
        u32 wdx = (u32)gr / 49u; int nn = gr - (int)wdx * 49;
        int bb = (int)(wdx >> 8); int wl = (int)(wdx & 255);
        int wh = wl >> 4, wwi = wl & 15;
        int ii = (int)((u32)nn / 7u), jj = nn - ii * 7;
        int th = wh * 7 + ii + 3;  if (th >= 112) th -= 112;
        int tw = wwi * 7 + jj + 3; if (tw >= 112) tw -= 112;
        u32 adr = (u32)(bb * 12544 + th * 112 + tw) * 192u;
        #pragma unroll
        for (int t = 0; t < 3; ++t)
          #pragma unroll
          for (int n = 0; n < 2; ++n){
            const int col = t*64 + wc*32 + n*16 + lr;
            of[adr + (u32)col] += acc[t][m][n][r];
          }
      }
  }
}

// ------------------------------- attention ---------------------------------
// one wave per (window, head); 4 waves / block.  49 padded to 64.
__global__ __launch_bounds__(256, 4)
void attn_k(const u16* __restrict__ qkv, const float* __restrict__ bmt,
            u16* __restrict__ aout){
  __shared__ __align__(16) u16 plds[4][64 * 64];   // 32 KB total
  const int wv = threadIdx.x >> 6, lnn = threadIdx.x & 63;
  const int lr = lnn & 15, lg = lnn >> 4;
  const u32 gid = (u32)blockIdx.x * 4u + (u32)wv;   // < 49152
  const u32 w = gid / 6u; const int h = (int)(gid - w * 6u);
  const u16* qb = qkv + (size_t)gid * 1568;
  const u16* kb = qb + HSTR;
  const u16* vb = kb + HSTR;

  // C-init = bias+mask table (b128 per lane, L2/L3-resident)
  const int wl = (int)(w & 255);
  const int cls = (((wl >> 4) == 15) ? 2 : 0) | (((wl & 15) == 15) ? 1 : 0);
  const float* bmv = bmt + ((u32)(cls * 6 + h) << 12);
  v4f s[4][4];
  #pragma unroll
  for (int m = 0; m < 4; ++m)
    #pragma unroll
    for (int n = 0; n < 4; ++n)
      s[m][n] = *(const v4f*)&bmv[(u32)(((m*4 + n)*16 + lr)*16 + lg*4)];

  // Q.K^T on top of bias
  v8bf aq[4], bk4[4];
  #pragma unroll
  for (int m = 0; m < 4; ++m) aq[m]  = *(const v8bf*)(qb + (m*16 + lr)*32 + lg*8);
  #pragma unroll
  for (int n = 0; n < 4; ++n) bk4[n] = *(const v8bf*)(kb + (n*16 + lr)*32 + lg*8);
  #pragma unroll
  for (int m = 0; m < 4; ++m)
    #pragma unroll
    for (int n = 0; n < 4; ++n) s[m][n] = MFMA16(aq[m], bk4[n], s[m][n]);

  // V fragments from global, k-permuted (pads multiply P==0 -> harmless)
  v8u16 bvu[2][2];
  #pragma unroll
  for (int n2 = 0; n2 < 2; ++n2)
    #pragma unroll
    for (int ksi = 0; ksi < 2; ++ksi)
      #pragma unroll
      for (int e = 0; e < 8; ++e){
        int kp = ksi * 32 + lg * 8 + e;
        int t  = (kp >> 2) + (kp & 3) * 16;
        bvu[n2][ksi][e] = vb[(u32)(t * 32 + n2 * 16 + lr)];
      }

  // P = exp(s), packed store (pos = lr*4+n), XOR-swizzled rows
  #pragma unroll
  for (int m = 0; m < 4; ++m)
    #pragma unroll
    for (int r = 0; r < 4; ++r){
      int row = m*16 + lg*4 + r;
      v4u16 pk;
      pk[0] = f2bf(__expf(s[m][0][r]));
      pk[1] = f2bf(__expf(s[m][1][r]));
      pk[2] = f2bf(__expf(s[m][2][r]));
      pk[3] = f2bf(__expf(s[m][3][r]));
      *(v4u16*)((char*)&plds[wv][0] + row*128 + ((lr*8) ^ ((row & 7) << 4))) = pk;
    }

  v8bf pa[4][2];
  #pragma unroll
  for (int m2 = 0; m2 < 4; ++m2)
    #pragma unroll
    for (int ksi = 0; ksi < 2; ++ksi){
      int row2 = m2*16 + lr;
      pa[m2][ksi] = *(const v8bf*)((const char*)&plds[wv][0] + row2*128 +
                                   ((ksi*64 + lg*16) ^ ((row2 & 7) << 4)));
    }

  // ones B-frag (col 0 only) for row-sums
  v8u16 onesu;
  #pragma unroll
  for (int e = 0; e < 8; ++e) onesu[e] = (lr == 0) ? (u16)0x3F80 : (u16)0;
  const v8bf onesf = __builtin_bit_cast(v8bf, onesu);

  const v4f zf = {0.f, 0.f, 0.f, 0.f};
  v4f o2[4][2], sacc[4];
  #pragma unroll
  for (int m2 = 0; m2 < 4; ++m2){
    o2[m2][0] = zf; o2[m2][1] = zf; sacc[m2] = zf;
  }
  #pragma unroll
  for (int ksi = 0; ksi < 2; ++ksi)
    #pragma unroll
    for (int m2 = 0; m2 < 4; ++m2){
      o2[m2][0] = MFMA16(pa[m2][ksi], __builtin_bit_cast(v8bf, bvu[0][ksi]), o2[m2][0]);
      o2[m2][1] = MFMA16(pa[m2][ksi], __builtin_bit_cast(v8bf, bvu[1][ksi]), o2[m2][1]);
      sacc[m2]  = MFMA16(pa[m2][ksi], onesf, sacc[m2]);
    }

  float inv[4][4];
  #pragma unroll
  for (int m2 = 0; m2 < 4; ++m2)
    #pragma unroll
    for (int r = 0; r < 4; ++r)
      inv[m2][r] = 1.0f / __shfl(sacc[m2][r], lnn & 48, 64);

  #pragma unroll
  for (int m2 = 0; m2 < 4; ++m2){
    #pragma unroll
    for (int n2 = 0; n2 < 2; ++n2){
      #pragma unroll
      for (int r = 0; r < 4; ++r){
        int row = m2*16 + lg*4 + r;
        if (row < 49){
          float val = o2[m2][n2][r] * inv[m2][r];
          aout[(w * 49u + (u32)row) * 192u + (u32)(h*32 + n2*16 + lr)] = f2bf(val);
        }
      }
    }
  }
}

// ------------------------------ launcher -----------------------------------
extern "C" void kernel_launch(void* const* d_in, const int* in_sizes, int n_in,
                              void* d_out, int out_size, void* d_ws, size_t ws_size,
                              hipStream_t stream){
  const float* x     = (const float*)d_in[0];
  const float* n1g   = (const float*)d_in[1];
  const float* n1b   = (const float*)d_in[2];
  const float* qkvw  = (const float*)d_in[3];
  const float* qkvb  = (const float*)d_in[4];
  const float* rpb   = (const float*)d_in[5];
  const float* projw = (const float*)d_in[6];
  const float* projb = (const float*)d_in[7];
  const float* n2g   = (const float*)d_in[8];
  const float* n2b   = (const float*)d_in[9];
  const float* fc1w  = (const float*)d_in[10];
  const float* fc1b  = (const float*)d_in[11];
  const float* fc2w  = (const float*)d_in[12];
  const float* fc2b  = (const float*)d_in[13];
  float* out = (float*)d_out;

  char* ws  = (char*)d_ws;
  u16* bufA = (u16*)ws;                       // qkv 462MB -> h1 chunks
  u16* bufB = (u16*)(ws + 462422016L);        // xw -> attn_out -> xln2 (in place)
  u16* wq   = (u16*)(ws + 616562688L);
  u16* wp   = wq + 110592;
  u16* w1   = wp + 36864;
  u16* w2   = w1 + 147456;
  float* bmt = (float*)d_out;   // 98304 floats, consumed by attn before proj

  convk<<<432, 256, 0, stream>>>(qkvw,  wq, 110592);
  convk<<<144, 256, 0, stream>>>(projw, wp, 36864);
  convk<<<576, 256, 0, stream>>>(fc1w,  w1, 147456);
  convk<<<576, 256, 0, stream>>>(fc2w,  w2, 147456);
  bmt_k<<<384, 256, 0, stream>>>(rpb, bmt);

  // LN1 + shift + window partition
  ln_kern<<<25088, 256, 0, stream>>>(x, n1g, n1b, bufB);
  // qkv (M=401408, N=576, K=192) -> permuted q,k,v
  gemm_cl<0, 9><<<3136, 256, 0, stream>>>(bufB, 192, wq, 192, qkvb,
                                          bufA, nullptr, nullptr, nullptr, nullptr, 0);
  // windowed attention
  attn_k<<<12288, 256, 0, stream>>>(bufA, bmt, bufB);
  // proj + residual -> x1 (fp32, d_out)  +  LN2 -> xln2 (bf16, bufB in place)
  gemm_cl<1, 3><<<3136, 256, 0, stream>>>(bufB, 192, wp, 192, projb,
                                          bufB, out, x, n2g, n2b, 0);
  // MLP in 2 window-row chunks (h1 chunk reuses bufA); fc2 scatters to tokens
  for (int c = 0; c < 2; ++c){
    int off = c * 200704;
    gemm_cl<2, 12><<<1568, 256, 0, stream>>>(bufB + (size_t)off * 192, 192,
                                             w1, 192, fc1b,
                                             bufA, nullptr, nullptr, nullptr, nullptr, 0);
    gemm_cl<3, 3><<<1568, 256, 0, stream>>>(bufA, 768, w2, 768, fc2b,
                                            nullptr, out, nullptr, nullptr, nullptr, off);
  }
}

// Round 5
// 1446.980 us; speedup vs baseline: 1.4258x; 1.4258x over previous
//
#include <hip/hip_runtime.h>
#include <stdint.h>
#include <math.h>

// ---------------------------------------------------------------------------
// Swin block, MI355X. B=32 H=W=112 C=192 NH=6 hd=32 WS=7 SS=3 -> 8192 windows,
// 49 tokens, 401408 token-rows.
// R4 regressed (col-loop GEMM = latency-bound, occupancy 10%). R5 = R3's
// fully-parallel gemm_bt + XCD-aligned group swizzle: 1D grid, groups of
// G=56 row-blocks x all col-blocks, col-major inside the group so the 9/12/3
// col-blocks sharing an A-tile are dispatch-adjacent AND land on the same XCD
// (56%8==0 -> bid%8 == row_local%8). A-tile fetched once per XCD-L2.
// ---------------------------------------------------------------------------

typedef unsigned short u16;
typedef unsigned int   u32;
typedef __bf16 v8bf __attribute__((ext_vector_type(8)));
typedef float  v4f  __attribute__((ext_vector_type(4)));
typedef u16    v8u16 __attribute__((ext_vector_type(8)));
typedef u16    v4u16 __attribute__((ext_vector_type(4)));

#define MFMA16(a,b,c) __builtin_amdgcn_mfma_f32_16x16x32_bf16(a,b,c,0,0,0)

#define HSTR 77070336L          // elems per q/k/v array (8192*6*49*32)

__device__ __forceinline__ u16 f2bf(float f){
  u32 u = __builtin_bit_cast(u32, f);
  u32 r = u + 0x7FFFu + ((u >> 16) & 1u);   // RNE
  return (u16)(r >> 16);
}

__device__ __forceinline__ void async16(void* lds, const void* g){
  __builtin_amdgcn_global_load_lds(
      (__attribute__((address_space(1))) void*)(g),
      (__attribute__((address_space(3))) void*)(lds), 16, 0, 0);
}

// ------------------------------ weight convert -----------------------------
__global__ __launch_bounds__(256) void convk(const float* __restrict__ s,
                                             u16* __restrict__ d, int n){
  int i = blockIdx.x * 256 + threadIdx.x;
  if (i < n) d[i] = f2bf(s[i]);
}

// -------------------- fused rel-pos-bias + shift-mask table ----------------
// layout: [cls][h][m][n][lr][lg*4+r]  (matches MFMA C fragment, b128/lane)
__global__ __launch_bounds__(256)
void bmt_k(const float* __restrict__ rpb, float* __restrict__ bmt){
  int idx = blockIdx.x * 256 + threadIdx.x;      // 98304 total
  int r  = idx & 3, lg = (idx >> 2) & 3, lr = (idx >> 4) & 15;
  int n  = (idx >> 8) & 3, m = (idx >> 10) & 3;
  int t  = idx >> 12; int h = t % 6, cls = t / 6;
  int row = m*16 + lg*4 + r, col = n*16 + lr;
  float v;
  if (row >= 49 || col >= 49){
    v = -1e30f;
  } else {
    int i1 = row / 7, j1 = row - i1 * 7;
    int i2 = col / 7, j2 = col - i2 * 7;
    int ridx = (i1 - i2 + 6) * 13 + (j1 - j2 + 6);
    v = rpb[ridx * 6 + h];
    int lh1 = (cls & 2) ? (i1 < 4 ? 1 : 2) : 0;
    int lw1 = (cls & 1) ? (j1 < 4 ? 1 : 2) : 0;
    int lh2 = (cls & 2) ? (i2 < 4 ? 1 : 2) : 0;
    int lw2 = (cls & 1) ? (j2 < 4 ? 1 : 2) : 0;
    if (lh1 * 3 + lw1 != lh2 * 3 + lw2) v -= 100.f;
  }
  bmt[idx] = v;
}

// ----------------------- LayerNorm (optionally gathered) -------------------
// 16 lanes per token, 4 tokens per wave; lane handles 12 channels (3 float4).
template<bool GATHER>
__global__ __launch_bounds__(256)
void ln_kern(const float* __restrict__ x, const float* __restrict__ g,
             const float* __restrict__ b, u16* __restrict__ o){
  const int ts  = threadIdx.x >> 4;
  const int l16 = threadIdx.x & 15;
  const int r   = blockIdx.x * 16 + ts;          // < 401408
  const float* src;
  if (GATHER){
    u32 wdx = (u32)r / 49u; int nn = r - (int)wdx * 49;
    int bb = (int)(wdx >> 8); int wl = (int)(wdx & 255);
    int wh = wl >> 4, wwi = wl & 15;
    int ii = (int)((u32)nn / 7u), jj = nn - ii * 7;
    int th = wh * 7 + ii + 3;  if (th >= 112) th -= 112;
    int tw = wwi * 7 + jj + 3; if (tw >= 112) tw -= 112;
    src = x + (u32)(bb * 12544 + th * 112 + tw) * 192u;
  } else {
    src = x + (u32)r * 192u;
  }
  const float4 a0 = *(const float4*)(src + l16*12);
  const float4 a1 = *(const float4*)(src + l16*12 + 4);
  const float4 a2 = *(const float4*)(src + l16*12 + 8);
  float sm = ((a0.x+a0.y)+(a0.z+a0.w)) + ((a1.x+a1.y)+(a1.z+a1.w))
           + ((a2.x+a2.y)+(a2.z+a2.w));
  float sq = ((a0.x*a0.x+a0.y*a0.y)+(a0.z*a0.z+a0.w*a0.w))
           + ((a1.x*a1.x+a1.y*a1.y)+(a1.z*a1.z+a1.w*a1.w))
           + ((a2.x*a2.x+a2.y*a2.y)+(a2.z*a2.z+a2.w*a2.w));
  #pragma unroll
  for (int d = 1; d < 16; d <<= 1){
    sm += __shfl_xor(sm, d, 64);
    sq += __shfl_xor(sq, d, 64);
  }
  float mean = sm * (1.f/192.f);
  float var  = sq * (1.f/192.f) - mean * mean;
  float rs   = rsqrtf(var + 1e-5f);
  const float4 g0 = *(const float4*)(g + l16*12);
  const float4 g1 = *(const float4*)(g + l16*12 + 4);
  const float4 g2 = *(const float4*)(g + l16*12 + 8);
  const float4 b0 = *(const float4*)(b + l16*12);
  const float4 b1 = *(const float4*)(b + l16*12 + 4);
  const float4 b2 = *(const float4*)(b + l16*12 + 8);
  u16* dst = o + (u32)r * 192u + l16 * 12;
  v4u16 w0, w1, w2;
  w0[0]=f2bf((a0.x-mean)*rs*g0.x+b0.x); w0[1]=f2bf((a0.y-mean)*rs*g0.y+b0.y);
  w0[2]=f2bf((a0.z-mean)*rs*g0.z+b0.z); w0[3]=f2bf((a0.w-mean)*rs*g0.w+b0.w);
  w1[0]=f2bf((a1.x-mean)*rs*g1.x+b1.x); w1[1]=f2bf((a1.y-mean)*rs*g1.y+b1.y);
  w1[2]=f2bf((a1.z-mean)*rs*g1.z+b1.z); w1[3]=f2bf((a1.w-mean)*rs*g1.w+b1.w);
  w2[0]=f2bf((a2.x-mean)*rs*g2.x+b2.x); w2[1]=f2bf((a2.y-mean)*rs*g2.y+b2.y);
  w2[2]=f2bf((a2.z-mean)*rs*g2.z+b2.z); w2[3]=f2bf((a2.w-mean)*rs*g2.w+b2.w);
  *(v4u16*)(dst)     = w0;
  *(v4u16*)(dst + 4) = w1;
  *(v4u16*)(dst + 8) = w2;
}

// ------------------------------- GEMM (A @ W^T) ----------------------------
// BM=128, BN=64, BK=192/stage. 1D grid with XCD-aligned group swizzle:
// groups of G=56 row-blocks x ncol col-blocks, col-major inside the group.
// bid%8 == row_local%8 (56%8==0, 56*ncol%8==0) -> all col-blocks of one row
// hit the same XCD's L2; they are also dispatch-adjacent.
template<int EPI>
__global__ __launch_bounds__(256)
void gemm_bt(const u16* __restrict__ A, int ldA, int aRowOff,
             const u16* __restrict__ W, int ldW, int K, int ncol,
             const float* __restrict__ bias,
             u16* __restrict__ ob, float* __restrict__ of,
             const float* __restrict__ xres, int oRowOff){
  __shared__ __align__(16) u16 sA[128 * 200];
  __shared__ __align__(16) u16 sW[64 * 200];
  const int tid = threadIdx.x;
  const int wv = tid >> 6, lnn = tid & 63;
  const int lr = lnn & 15, lg = lnn >> 4;
  // group swizzle
  const int win = 56 * ncol;
  const int grp = (int)blockIdx.x / win, loc = (int)blockIdx.x - grp * win;
  const int rloc = loc % 56, cblk = loc / 56;
  const int m0   = (grp * 56 + rloc) * 128;
  const int col0 = cblk * 64;
  const int wr = wv >> 1, wc = wv & 1;

  const float b0v = bias[col0 + wc*32 + lr];
  const float b1v = bias[col0 + wc*32 + 16 + lr];
  v4f acc[4][2];
  #pragma unroll
  for (int m = 0; m < 4; ++m){
    acc[m][0] = (v4f){b0v, b0v, b0v, b0v};
    acc[m][1] = (v4f){b1v, b1v, b1v, b1v};
  }

  const int rA0 = (int)((u32)tid / 25u);
  const int cA0 = tid - rA0 * 25;
  const u32 aBase = (u32)(aRowOff + m0);
  const int nK = K / 192;
  for (int ks = 0; ks < nK; ++ks){
    if (ks) __syncthreads();
    const int k0 = ks * 192;
    // A tile: 128 rows x 25 chunks(16B); chunk 24 re-reads tail (LDS linear)
    int ra = rA0, ca = cA0;
    #pragma unroll
    for (int it = 0; it < 12; ++it){
      int cc = (ca == 24) ? 23 : ca;
      async16((char*)sA + (size_t)(it * 256 + wv * 64) * 16,
              A + (aBase + (u32)ra) * (u32)ldA + (u32)(k0 + cc * 8));
      ra += 10; ca += 6; if (ca >= 25){ ca -= 25; ra += 1; }
    }
    if (wv < 2){
      int cc = (ca == 24) ? 23 : ca;
      async16((char*)sA + (size_t)(3072 + wv * 64) * 16,
              A + (aBase + (u32)ra) * (u32)ldA + (u32)(k0 + cc * 8));
    }
    // W tile: 64 rows x 25 chunks
    int rw = rA0, cw = cA0;
    #pragma unroll
    for (int it = 0; it < 6; ++it){
      int cc = (cw == 24) ? 23 : cw;
      async16((char*)sW + (size_t)(it * 256 + wv * 64) * 16,
              W + (u32)(col0 + rw) * (u32)ldW + (u32)(k0 + cc * 8));
      rw += 10; cw += 6; if (cw >= 25){ cw -= 25; rw += 1; }
    }
    if (wv == 0){
      int cc = (cw == 24) ? 23 : cw;
      async16((char*)sW + (size_t)1536 * 16,
              W + (u32)(col0 + rw) * (u32)ldW + (u32)(k0 + cc * 8));
    }
    __syncthreads();   // drains vmcnt(0) -> staged data visible

    #pragma unroll
    for (int kk = 0; kk < 6; ++kk){
      v8bf af[4], wf[2];
      #pragma unroll
      for (int m = 0; m < 4; ++m)
        af[m] = *(const v8bf*)&sA[(wr*64 + m*16 + lr) * 200 + kk*32 + lg*8];
      #pragma unroll
      for (int n = 0; n < 2; ++n)
        wf[n] = *(const v8bf*)&sW[(wc*32 + n*16 + lr) * 200 + kk*32 + lg*8];
      #pragma unroll
      for (int m = 0; m < 4; ++m)
        #pragma unroll
        for (int n = 0; n < 2; ++n)
          acc[m][n] = MFMA16(af[m], wf[n], acc[m][n]);
    }
  }

  // epilogue (32-bit index math).  D layout: row = 4*lg + r, col = lr
  #pragma unroll
  for (int m = 0; m < 4; ++m){
    #pragma unroll
    for (int n = 0; n < 2; ++n){
      #pragma unroll
      for (int r = 0; r < 4; ++r){
        const int lrow = m0 + wr*64 + m*16 + lg*4 + r;
        const int col  = col0 + wc*32 + n*16 + lr;
        float val = acc[m][n][r];
        if (EPI == 0){
          int which = (col >= 384) ? 2 : ((col >= 192) ? 1 : 0);
          int rem = col - which * 192;
          int hh = rem >> 5, dd = rem & 31;
          if (which == 0) val *= 0.17677669529663687f;  // hd^-0.5
          u32 wdx = (u32)lrow / 49u; u32 nn = (u32)lrow - wdx * 49u;
          ob[(u32)which * 77070336u + ((wdx*6u + (u32)hh)*49u + nn)*32u + (u32)dd]
              = f2bf(val);
        } else if (EPI == 1){
          u32 wdx = (u32)lrow / 49u; int nn = lrow - (int)wdx * 49;
          int bb = (int)(wdx >> 8); int wl = (int)(wdx & 255);
          int wh = wl >> 4, wwi = wl & 15;
          int ii = (int)((u32)nn / 7u), jj = nn - ii * 7;
          int th = wh * 7 + ii + 3;  if (th >= 112) th -= 112;
          int tw = wwi * 7 + jj + 3; if (tw >= 112) tw -= 112;
          u32 adr = (u32)(bb * 12544 + th * 112 + tw) * 192u + (u32)col;
          of[adr] = xres[adr] + val;
        } else if (EPI == 2){
          float gg = 0.5f * val * (1.0f + erff(val * 0.7071067811865475f));
          ob[(u32)lrow * 768u + (u32)col] = f2bf(gg);
        } else {
          of[(u32)(oRowOff + lrow) * 192u + (u32)col] += val;
        }
      }
    }
  }
}

// ------------------------------- attention ---------------------------------
// one wave per (window, head); 4 waves / block.  49 padded to 64.
// Scores bounded -> no max pass; masked (-100) / pad (-1e30) underflow to 0.
__global__ __launch_bounds__(256, 4)
void attn_k(const u16* __restrict__ qkv, const float* __restrict__ bmt,
            u16* __restrict__ aout){
  __shared__ __align__(16) u16 plds[4][64 * 64];   // 32 KB total
  const int wv = threadIdx.x >> 6, lnn = threadIdx.x & 63;
  const int lr = lnn & 15, lg = lnn >> 4;
  const u32 gid = (u32)blockIdx.x * 4u + (u32)wv;   // < 49152
  const u32 w = gid / 6u; const int h = (int)(gid - w * 6u);
  const u16* qb = qkv + (size_t)gid * 1568;
  const u16* kb = qb + HSTR;
  const u16* vb = kb + HSTR;

  // C-init = bias+mask table (b128 per lane, L2/L3-resident)
  const int wl = (int)(w & 255);
  const int cls = (((wl >> 4) == 15) ? 2 : 0) | (((wl & 15) == 15) ? 1 : 0);
  const float* bmv = bmt + ((u32)(cls * 6 + h) << 12);
  v4f s[4][4];
  #pragma unroll
  for (int m = 0; m < 4; ++m)
    #pragma unroll
    for (int n = 0; n < 4; ++n)
      s[m][n] = *(const v4f*)&bmv[(u32)(((m*4 + n)*16 + lr)*16 + lg*4)];

  // Q.K^T on top of bias
  v8bf aq[4], bk4[4];
  #pragma unroll
  for (int m = 0; m < 4; ++m) aq[m]  = *(const v8bf*)(qb + (m*16 + lr)*32 + lg*8);
  #pragma unroll
  for (int n = 0; n < 4; ++n) bk4[n] = *(const v8bf*)(kb + (n*16 + lr)*32 + lg*8);
  #pragma unroll
  for (int m = 0; m < 4; ++m)
    #pragma unroll
    for (int n = 0; n < 4; ++n) s[m][n] = MFMA16(aq[m], bk4[n], s[m][n]);

  // V fragments from global, k-permuted (pads multiply P==0 -> harmless)
  v8u16 bvu[2][2];
  #pragma unroll
  for (int n2 = 0; n2 < 2; ++n2)
    #pragma unroll
    for (int ksi = 0; ksi < 2; ++ksi)
      #pragma unroll
      for (int e = 0; e < 8; ++e){
        int kp = ksi * 32 + lg * 8 + e;
        int t  = (kp >> 2) + (kp & 3) * 16;
        bvu[n2][ksi][e] = vb[(u32)(t * 32 + n2 * 16 + lr)];
      }

  // P = exp(s), packed store (pos = lr*4+n), XOR-swizzled rows
  #pragma unroll
  for (int m = 0; m < 4; ++m)
    #pragma unroll
    for (int r = 0; r < 4; ++r){
      int row = m*16 + lg*4 + r;
      v4u16 pk;
      pk[0] = f2bf(__expf(s[m][0][r]));
      pk[1] = f2bf(__expf(s[m][1][r]));
      pk[2] = f2bf(__expf(s[m][2][r]));
      pk[3] = f2bf(__expf(s[m][3][r]));
      *(v4u16*)((char*)&plds[wv][0] + row*128 + ((lr*8) ^ ((row & 7) << 4))) = pk;
    }

  v8bf pa[4][2];
  #pragma unroll
  for (int m2 = 0; m2 < 4; ++m2)
    #pragma unroll
    for (int ksi = 0; ksi < 2; ++ksi){
      int row2 = m2*16 + lr;
      pa[m2][ksi] = *(const v8bf*)((const char*)&plds[wv][0] + row2*128 +
                                   ((ksi*64 + lg*16) ^ ((row2 & 7) << 4)));
    }

  // ones B-frag (col 0 only) for row-sums
  v8u16 onesu;
  #pragma unroll
  for (int e = 0; e < 8; ++e) onesu[e] = (lr == 0) ? (u16)0x3F80 : (u16)0;
  const v8bf onesf = __builtin_bit_cast(v8bf, onesu);

  const v4f zf = {0.f, 0.f, 0.f, 0.f};
  v4f o2[4][2], sacc[4];
  #pragma unroll
  for (int m2 = 0; m2 < 4; ++m2){
    o2[m2][0] = zf; o2[m2][1] = zf; sacc[m2] = zf;
  }
  #pragma unroll
  for (int ksi = 0; ksi < 2; ++ksi)
    #pragma unroll
    for (int m2 = 0; m2 < 4; ++m2){
      o2[m2][0] = MFMA16(pa[m2][ksi], __builtin_bit_cast(v8bf, bvu[0][ksi]), o2[m2][0]);
      o2[m2][1] = MFMA16(pa[m2][ksi], __builtin_bit_cast(v8bf, bvu[1][ksi]), o2[m2][1]);
      sacc[m2]  = MFMA16(pa[m2][ksi], onesf, sacc[m2]);
    }

  float inv[4][4];
  #pragma unroll
  for (int m2 = 0; m2 < 4; ++m2)
    #pragma unroll
    for (int r = 0; r < 4; ++r)
      inv[m2][r] = 1.0f / __shfl(sacc[m2][r], lnn & 48, 64);

  #pragma unroll
  for (int m2 = 0; m2 < 4; ++m2){
    #pragma unroll
    for (int n2 = 0; n2 < 2; ++n2){
      #pragma unroll
      for (int r = 0; r < 4; ++r){
        int row = m2*16 + lg*4 + r;
        if (row < 49){
          float val = o2[m2][n2][r] * inv[m2][r];
          aout[(w * 49u + (u32)row) * 192u + (u32)(h*32 + n2*16 + lr)] = f2bf(val);
        }
      }
    }
  }
}

// ------------------------------ launcher -----------------------------------
extern "C" void kernel_launch(void* const* d_in, const int* in_sizes, int n_in,
                              void* d_out, int out_size, void* d_ws, size_t ws_size,
                              hipStream_t stream){
  const float* x     = (const float*)d_in[0];
  const float* n1g   = (const float*)d_in[1];
  const float* n1b   = (const float*)d_in[2];
  const float* qkvw  = (const float*)d_in[3];
  const float* qkvb  = (const float*)d_in[4];
  const float* rpb   = (const float*)d_in[5];
  const float* projw = (const float*)d_in[6];
  const float* projb = (const float*)d_in[7];
  const float* n2g   = (const float*)d_in[8];
  const float* n2b   = (const float*)d_in[9];
  const float* fc1w  = (const float*)d_in[10];
  const float* fc1b  = (const float*)d_in[11];
  const float* fc2w  = (const float*)d_in[12];
  const float* fc2b  = (const float*)d_in[13];
  float* out = (float*)d_out;

  char* ws  = (char*)d_ws;
  u16* bufA = (u16*)ws;                       // qkv 462MB -> h1 chunks
  u16* bufB = (u16*)(ws + 462422016L);        // xw -> attn_out -> xln2
  u16* wq   = (u16*)(ws + 616562688L);
  u16* wp   = wq + 110592;
  u16* w1   = wp + 36864;
  u16* w2   = w1 + 147456;
  float* bmt = (float*)d_out;   // 98304 floats, consumed by attn before proj

  convk<<<432, 256, 0, stream>>>(qkvw,  wq, 110592);
  convk<<<144, 256, 0, stream>>>(projw, wp, 36864);
  convk<<<576, 256, 0, stream>>>(fc1w,  w1, 147456);
  convk<<<576, 256, 0, stream>>>(fc2w,  w2, 147456);
  bmt_k<<<384, 256, 0, stream>>>(rpb, bmt);

  // LN1 + shift + window partition
  ln_kern<true><<<25088, 256, 0, stream>>>(x, n1g, n1b, bufB);
  // qkv (M=401408, N=576, K=192) -> permuted q,k,v.  grid = 3136*9 swizzled
  gemm_bt<0><<<3136*9, 256, 0, stream>>>(bufB, 192, 0, wq, 192, 192, 9,
                                         qkvb, bufA, nullptr, nullptr, 0);
  // windowed attention
  attn_k<<<12288, 256, 0, stream>>>(bufA, bmt, bufB);
  // proj (N=192) + scatter + residual -> d_out
  gemm_bt<1><<<3136*3, 256, 0, stream>>>(bufB, 192, 0, wp, 192, 192, 3,
                                         projb, nullptr, out, x, 0);
  // LN2
  ln_kern<false><<<25088, 256, 0, stream>>>(out, n2g, n2b, bufB);
  // MLP in 2 token-chunks (h1 chunk reuses bufA)
  for (int c = 0; c < 2; ++c){
    int off = c * 200704;
    gemm_bt<2><<<1568*12, 256, 0, stream>>>(bufB, 192, off, w1, 192, 192, 12,
                                            fc1b, bufA, nullptr, nullptr, 0);
    gemm_bt<3><<<1568*3, 256, 0, stream>>>(bufA, 768, 0, w2, 768, 768, 3,
                                           fc2b, nullptr, out, nullptr, off);
  }
}

// Round 6
// 1376.641 us; speedup vs baseline: 1.4987x; 1.0511x over previous
//
#include <hip/hip_runtime.h>
#include <stdint.h>
#include <math.h>

// ---------------------------------------------------------------------------
// Swin block, MI355X. B=32 H=W=112 C=192 NH=6 hd=32 WS=7 SS=3 -> 8192 windows,
// 49 tokens, 401408 token-rows.
// R5: gemm_bt + XCD-aligned group swizzle (FETCH fixed). R6: gemm_bt goes
// 512-thread / 8-wave (32x32 per wave): 16 waves/CU (2 blocks x 8) instead of
// 8, halved per-thread epilogue VALU -> hides single-shot stage latency.
// ---------------------------------------------------------------------------

typedef unsigned short u16;
typedef unsigned int   u32;
typedef __bf16 v8bf __attribute__((ext_vector_type(8)));
typedef float  v4f  __attribute__((ext_vector_type(4)));
typedef u16    v8u16 __attribute__((ext_vector_type(8)));
typedef u16    v4u16 __attribute__((ext_vector_type(4)));

#define MFMA16(a,b,c) __builtin_amdgcn_mfma_f32_16x16x32_bf16(a,b,c,0,0,0)

#define HSTR 77070336L          // elems per q/k/v array (8192*6*49*32)

__device__ __forceinline__ u16 f2bf(float f){
  u32 u = __builtin_bit_cast(u32, f);
  u32 r = u + 0x7FFFu + ((u >> 16) & 1u);   // RNE
  return (u16)(r >> 16);
}

__device__ __forceinline__ void async16(void* lds, const void* g){
  __builtin_amdgcn_global_load_lds(
      (__attribute__((address_space(1))) void*)(g),
      (__attribute__((address_space(3))) void*)(lds), 16, 0, 0);
}

// --------------------- combined weight convert (contiguous dst) ------------
__global__ __launch_bounds__(256)
void convw(const float* __restrict__ s0, const float* __restrict__ s1,
           const float* __restrict__ s2, const float* __restrict__ s3,
           u16* __restrict__ d){
  int i = blockIdx.x * 256 + threadIdx.x;        // < 442368
  float v;
  if (i < 110592)       v = s0[i];
  else if (i < 147456)  v = s1[i - 110592];
  else if (i < 294912)  v = s2[i - 147456];
  else                  v = s3[i - 294912];
  d[i] = f2bf(v);
}

// -------------------- fused rel-pos-bias + shift-mask table ----------------
// layout: [cls][h][m][n][lr][lg*4+r]  (matches MFMA C fragment, b128/lane)
__global__ __launch_bounds__(256)
void bmt_k(const float* __restrict__ rpb, float* __restrict__ bmt){
  int idx = blockIdx.x * 256 + threadIdx.x;      // 98304 total
  int r  = idx & 3, lg = (idx >> 2) & 3, lr = (idx >> 4) & 15;
  int n  = (idx >> 8) & 3, m = (idx >> 10) & 3;
  int t  = idx >> 12; int h = t % 6, cls = t / 6;
  int row = m*16 + lg*4 + r, col = n*16 + lr;
  float v;
  if (row >= 49 || col >= 49){
    v = -1e30f;
  } else {
    int i1 = row / 7, j1 = row - i1 * 7;
    int i2 = col / 7, j2 = col - i2 * 7;
    int ridx = (i1 - i2 + 6) * 13 + (j1 - j2 + 6);
    v = rpb[ridx * 6 + h];
    int lh1 = (cls & 2) ? (i1 < 4 ? 1 : 2) : 0;
    int lw1 = (cls & 1) ? (j1 < 4 ? 1 : 2) : 0;
    int lh2 = (cls & 2) ? (i2 < 4 ? 1 : 2) : 0;
    int lw2 = (cls & 1) ? (j2 < 4 ? 1 : 2) : 0;
    if (lh1 * 3 + lw1 != lh2 * 3 + lw2) v -= 100.f;
  }
  bmt[idx] = v;
}

// ----------------------- LayerNorm (optionally gathered) -------------------
// 16 lanes per token, 4 tokens per wave; lane handles 12 channels (3 float4).
template<bool GATHER>
__global__ __launch_bounds__(256)
void ln_kern(const float* __restrict__ x, const float* __restrict__ g,
             const float* __restrict__ b, u16* __restrict__ o){
  const int ts  = threadIdx.x >> 4;
  const int l16 = threadIdx.x & 15;
  const int r   = blockIdx.x * 16 + ts;          // < 401408
  const float* src;
  if (GATHER){
    u32 wdx = (u32)r / 49u; int nn = r - (int)wdx * 49;
    int bb = (int)(wdx >> 8); int wl = (int)(wdx & 255);
    int wh = wl >> 4, wwi = wl & 15;
    int ii = (int)((u32)nn / 7u), jj = nn - ii * 7;
    int th = wh * 7 + ii + 3;  if (th >= 112) th -= 112;
    int tw = wwi * 7 + jj + 3; if (tw >= 112) tw -= 112;
    src = x + (u32)(bb * 12544 + th * 112 + tw) * 192u;
  } else {
    src = x + (u32)r * 192u;
  }
  const float4 a0 = *(const float4*)(src + l16*12);
  const float4 a1 = *(const float4*)(src + l16*12 + 4);
  const float4 a2 = *(const float4*)(src + l16*12 + 8);
  float sm = ((a0.x+a0.y)+(a0.z+a0.w)) + ((a1.x+a1.y)+(a1.z+a1.w))
           + ((a2.x+a2.y)+(a2.z+a2.w));
  float sq = ((a0.x*a0.x+a0.y*a0.y)+(a0.z*a0.z+a0.w*a0.w))
           + ((a1.x*a1.x+a1.y*a1.y)+(a1.z*a1.z+a1.w*a1.w))
           + ((a2.x*a2.x+a2.y*a2.y)+(a2.z*a2.z+a2.w*a2.w));
  #pragma unroll
  for (int d = 1; d < 16; d <<= 1){
    sm += __shfl_xor(sm, d, 64);
    sq += __shfl_xor(sq, d, 64);
  }
  float mean = sm * (1.f/192.f);
  float var  = sq * (1.f/192.f) - mean * mean;
  float rs   = rsqrtf(var + 1e-5f);
  const float4 g0 = *(const float4*)(g + l16*12);
  const float4 g1 = *(const float4*)(g + l16*12 + 4);
  const float4 g2 = *(const float4*)(g + l16*12 + 8);
  const float4 b0 = *(const float4*)(b + l16*12);
  const float4 b1 = *(const float4*)(b + l16*12 + 4);
  const float4 b2 = *(const float4*)(b + l16*12 + 8);
  u16* dst = o + (u32)r * 192u + l16 * 12;
  v4u16 w0, w1, w2;
  w0[0]=f2bf((a0.x-mean)*rs*g0.x+b0.x); w0[1]=f2bf((a0.y-mean)*rs*g0.y+b0.y);
  w0[2]=f2bf((a0.z-mean)*rs*g0.z+b0.z); w0[3]=f2bf((a0.w-mean)*rs*g0.w+b0.w);
  w1[0]=f2bf((a1.x-mean)*rs*g1.x+b1.x); w1[1]=f2bf((a1.y-mean)*rs*g1.y+b1.y);
  w1[2]=f2bf((a1.z-mean)*rs*g1.z+b1.z); w1[3]=f2bf((a1.w-mean)*rs*g1.w+b1.w);
  w2[0]=f2bf((a2.x-mean)*rs*g2.x+b2.x); w2[1]=f2bf((a2.y-mean)*rs*g2.y+b2.y);
  w2[2]=f2bf((a2.z-mean)*rs*g2.z+b2.z); w2[3]=f2bf((a2.w-mean)*rs*g2.w+b2.w);
  *(v4u16*)(dst)     = w0;
  *(v4u16*)(dst + 4) = w1;
  *(v4u16*)(dst + 8) = w2;
}

// ------------------------------- GEMM (A @ W^T) ----------------------------
// BM=128, BN=64, BK=192/stage, 512 threads = 8 waves, each wave a 32x32
// quadrant (wr = wv>>1 in 0..3, wc = wv&1).  1D grid, XCD-aligned group
// swizzle: groups of 56 row-blocks x ncol col-blocks, col-major in-group
// (56%8==0 -> bid%8 == row_local%8: col-blocks of a row share an XCD L2).
template<int EPI>
__global__ __launch_bounds__(512)
void gemm_bt(const u16* __restrict__ A, int ldA, int aRowOff,
             const u16* __restrict__ W, int ldW, int K, int ncol,
             const float* __restrict__ bias,
             u16* __restrict__ ob, float* __restrict__ of,
             const float* __restrict__ xres, int oRowOff){
  __shared__ __align__(16) u16 sA[128 * 200];
  __shared__ __align__(16) u16 sW[64 * 200];
  const int tid = threadIdx.x;
  const int wv = tid >> 6, lnn = tid & 63;
  const int lr = lnn & 15, lg = lnn >> 4;
  // group swizzle
  const int win = 56 * ncol;
  const int grp = (int)blockIdx.x / win, loc = (int)blockIdx.x - grp * win;
  const int rloc = loc % 56, cblk = loc / 56;
  const int m0   = (grp * 56 + rloc) * 128;
  const int col0 = cblk * 64;
  const int wr = wv >> 1, wc = wv & 1;

  const float b0v = bias[col0 + wc*32 + lr];
  const float b1v = bias[col0 + wc*32 + 16 + lr];
  v4f acc[2][2];
  #pragma unroll
  for (int m = 0; m < 2; ++m){
    acc[m][0] = (v4f){b0v, b0v, b0v, b0v};
    acc[m][1] = (v4f){b1v, b1v, b1v, b1v};
  }

  const int rA0 = (int)((u32)tid / 25u);
  const int cA0 = tid - rA0 * 25;
  const u32 aBase = (u32)(aRowOff + m0);
  const int nK = K / 192;
  for (int ks = 0; ks < nK; ++ks){
    if (ks) __syncthreads();
    const int k0 = ks * 192;
    // A tile: 128 rows x 25 chunks(16B) = 3200; 512 thr: 6 iters + 128-tail
    int ra = rA0, ca = cA0;
    #pragma unroll
    for (int it = 0; it < 6; ++it){
      int cc = (ca == 24) ? 23 : ca;
      async16((char*)sA + (size_t)(it * 512 + wv * 64) * 16,
              A + (aBase + (u32)ra) * (u32)ldA + (u32)(k0 + cc * 8));
      ra += 20; ca += 12; if (ca >= 25){ ca -= 25; ra += 1; }
    }
    if (tid < 128){
      int cc = (ca == 24) ? 23 : ca;
      async16((char*)sA + (size_t)(3072 + wv * 64) * 16,
              A + (aBase + (u32)ra) * (u32)ldA + (u32)(k0 + cc * 8));
    }
    // W tile: 64 rows x 25 chunks = 1600; 3 iters + 64-tail
    int rw = rA0, cw = cA0;
    #pragma unroll
    for (int it = 0; it < 3; ++it){
      int cc = (cw == 24) ? 23 : cw;
      async16((char*)sW + (size_t)(it * 512 + wv * 64) * 16,
              W + (u32)(col0 + rw) * (u32)ldW + (u32)(k0 + cc * 8));
      rw += 20; cw += 12; if (cw >= 25){ cw -= 25; rw += 1; }
    }
    if (tid < 64){
      int cc = (cw == 24) ? 23 : cw;
      async16((char*)sW + (size_t)1536 * 16,
              W + (u32)(col0 + rw) * (u32)ldW + (u32)(k0 + cc * 8));
    }
    __syncthreads();   // drains vmcnt(0) -> staged data visible

    #pragma unroll
    for (int kk = 0; kk < 6; ++kk){
      v8bf af[2], wf[2];
      #pragma unroll
      for (int m = 0; m < 2; ++m)
        af[m] = *(const v8bf*)&sA[(wr*32 + m*16 + lr) * 200 + kk*32 + lg*8];
      #pragma unroll
      for (int n = 0; n < 2; ++n)
        wf[n] = *(const v8bf*)&sW[(wc*32 + n*16 + lr) * 200 + kk*32 + lg*8];
      #pragma unroll
      for (int m = 0; m < 2; ++m)
        #pragma unroll
        for (int n = 0; n < 2; ++n)
          acc[m][n] = MFMA16(af[m], wf[n], acc[m][n]);
    }
  }

  // epilogue (32-bit index math).  D layout: row = 4*lg + r, col = lr
  #pragma unroll
  for (int m = 0; m < 2; ++m){
    #pragma unroll
    for (int n = 0; n < 2; ++n){
      #pragma unroll
      for (int r = 0; r < 4; ++r){
        const int lrow = m0 + wr*32 + m*16 + lg*4 + r;
        const int col  = col0 + wc*32 + n*16 + lr;
        float val = acc[m][n][r];
        if (EPI == 0){
          int which = (col >= 384) ? 2 : ((col >= 192) ? 1 : 0);
          int rem = col - which * 192;
          int hh = rem >> 5, dd = rem & 31;
          if (which == 0) val *= 0.17677669529663687f;  // hd^-0.5
          u32 wdx = (u32)lrow / 49u; u32 nn = (u32)lrow - wdx * 49u;
          ob[(u32)which * 77070336u + ((wdx*6u + (u32)hh)*49u + nn)*32u + (u32)dd]
              = f2bf(val);
        } else if (EPI == 1){
          u32 wdx = (u32)lrow / 49u; int nn = lrow - (int)wdx * 49;
          int bb = (int)(wdx >> 8); int wl = (int)(wdx & 255);
          int wh = wl >> 4, wwi = wl & 15;
          int ii = (int)((u32)nn / 7u), jj = nn - ii * 7;
          int th = wh * 7 + ii + 3;  if (th >= 112) th -= 112;
          int tw = wwi * 7 + jj + 3; if (tw >= 112) tw -= 112;
          u32 adr = (u32)(bb * 12544 + th * 112 + tw) * 192u + (u32)col;
          of[adr] = xres[adr] + val;
        } else if (EPI == 2){
          float gg = 0.5f * val * (1.0f + erff(val * 0.7071067811865475f));
          ob[(u32)lrow * 768u + (u32)col] = f2bf(gg);
        } else {
          of[(u32)(oRowOff + lrow) * 192u + (u32)col] += val;
        }
      }
    }
  }
}

// ------------------------------- attention ---------------------------------
// one wave per (window, head); 4 waves / block.  49 padded to 64.
// Scores bounded -> no max pass; masked (-100) / pad (-1e30) underflow to 0.
__global__ __launch_bounds__(256, 4)
void attn_k(const u16* __restrict__ qkv, const float* __restrict__ bmt,
            u16* __restrict__ aout){
  __shared__ __align__(16) u16 plds[4][64 * 64];   // 32 KB total
  const int wv = threadIdx.x >> 6, lnn = threadIdx.x & 63;
  const int lr = lnn & 15, lg = lnn >> 4;
  const u32 gid = (u32)blockIdx.x * 4u + (u32)wv;   // < 49152
  const u32 w = gid / 6u; const int h = (int)(gid - w * 6u);
  const u16* qb = qkv + (size_t)gid * 1568;
  const u16* kb = qb + HSTR;
  const u16* vb = kb + HSTR;

  // C-init = bias+mask table (b128 per lane, L2/L3-resident)
  const int wl = (int)(w & 255);
  const int cls = (((wl >> 4) == 15) ? 2 : 0) | (((wl & 15) == 15) ? 1 : 0);
  const float* bmv = bmt + ((u32)(cls * 6 + h) << 12);
  v4f s[4][4];
  #pragma unroll
  for (int m = 0; m < 4; ++m)
    #pragma unroll
    for (int n = 0; n < 4; ++n)
      s[m][n] = *(const v4f*)&bmv[(u32)(((m*4 + n)*16 + lr)*16 + lg*4)];

  // Q.K^T on top of bias
  v8bf aq[4], bk4[4];
  #pragma unroll
  for (int m = 0; m < 4; ++m) aq[m]  = *(const v8bf*)(qb + (m*16 + lr)*32 + lg*8);
  #pragma unroll
  for (int n = 0; n < 4; ++n) bk4[n] = *(const v8bf*)(kb + (n*16 + lr)*32 + lg*8);
  #pragma unroll
  for (int m = 0; m < 4; ++m)
    #pragma unroll
    for (int n = 0; n < 4; ++n) s[m][n] = MFMA16(aq[m], bk4[n], s[m][n]);

  // V fragments from global, k-permuted (pads multiply P==0 -> harmless)
  v8u16 bvu[2][2];
  #pragma unroll
  for (int n2 = 0; n2 < 2; ++n2)
    #pragma unroll
    for (int ksi = 0; ksi < 2; ++ksi)
      #pragma unroll
      for (int e = 0; e < 8; ++e){
        int kp = ksi * 32 + lg * 8 + e;
        int t  = (kp >> 2) + (kp & 3) * 16;
        bvu[n2][ksi][e] = vb[(u32)(t * 32 + n2 * 16 + lr)];
      }

  // P = exp(s), packed store (pos = lr*4+n), XOR-swizzled rows
  #pragma unroll
  for (int m = 0; m < 4; ++m)
    #pragma unroll
    for (int r = 0; r < 4; ++r){
      int row = m*16 + lg*4 + r;
      v4u16 pk;
      pk[0] = f2bf(__expf(s[m][0][r]));
      pk[1] = f2bf(__expf(s[m][1][r]));
      pk[2] = f2bf(__expf(s[m][2][r]));
      pk[3] = f2bf(__expf(s[m][3][r]));
      *(v4u16*)((char*)&plds[wv][0] + row*128 + ((lr*8) ^ ((row & 7) << 4))) = pk;
    }

  v8bf pa[4][2];
  #pragma unroll
  for (int m2 = 0; m2 < 4; ++m2)
    #pragma unroll
    for (int ksi = 0; ksi < 2; ++ksi){
      int row2 = m2*16 + lr;
      pa[m2][ksi] = *(const v8bf*)((const char*)&plds[wv][0] + row2*128 +
                                   ((ksi*64 + lg*16) ^ ((row2 & 7) << 4)));
    }

  // ones B-frag (col 0 only) for row-sums
  v8u16 onesu;
  #pragma unroll
  for (int e = 0; e < 8; ++e) onesu[e] = (lr == 0) ? (u16)0x3F80 : (u16)0;
  const v8bf onesf = __builtin_bit_cast(v8bf, onesu);

  const v4f zf = {0.f, 0.f, 0.f, 0.f};
  v4f o2[4][2], sacc[4];
  #pragma unroll
  for (int m2 = 0; m2 < 4; ++m2){
    o2[m2][0] = zf; o2[m2][1] = zf; sacc[m2] = zf;
  }
  #pragma unroll
  for (int ksi = 0; ksi < 2; ++ksi)
    #pragma unroll
    for (int m2 = 0; m2 < 4; ++m2){
      o2[m2][0] = MFMA16(pa[m2][ksi], __builtin_bit_cast(v8bf, bvu[0][ksi]), o2[m2][0]);
      o2[m2][1] = MFMA16(pa[m2][ksi], __builtin_bit_cast(v8bf, bvu[1][ksi]), o2[m2][1]);
      sacc[m2]  = MFMA16(pa[m2][ksi], onesf, sacc[m2]);
    }

  float inv[4][4];
  #pragma unroll
  for (int m2 = 0; m2 < 4; ++m2)
    #pragma unroll
    for (int r = 0; r < 4; ++r)
      inv[m2][r] = 1.0f / __shfl(sacc[m2][r], lnn & 48, 64);

  #pragma unroll
  for (int m2 = 0; m2 < 4; ++m2){
    #pragma unroll
    for (int n2 = 0; n2 < 2; ++n2){
      #pragma unroll
      for (int r = 0; r < 4; ++r){
        int row = m2*16 + lg*4 + r;
        if (row < 49){
          float val = o2[m2][n2][r] * inv[m2][r];
          aout[(w * 49u + (u32)row) * 192u + (u32)(h*32 + n2*16 + lr)] = f2bf(val);
        }
      }
    }
  }
}

// ------------------------------ launcher -----------------------------------
extern "C" void kernel_launch(void* const* d_in, const int* in_sizes, int n_in,
                              void* d_out, int out_size, void* d_ws, size_t ws_size,
                              hipStream_t stream){
  const float* x     = (const float*)d_in[0];
  const float* n1g   = (const float*)d_in[1];
  const float* n1b   = (const float*)d_in[2];
  const float* qkvw  = (const float*)d_in[3];
  const float* qkvb  = (const float*)d_in[4];
  const float* rpb   = (const float*)d_in[5];
  const float* projw = (const float*)d_in[6];
  const float* projb = (const float*)d_in[7];
  const float* n2g   = (const float*)d_in[8];
  const float* n2b   = (const float*)d_in[9];
  const float* fc1w  = (const float*)d_in[10];
  const float* fc1b  = (const float*)d_in[11];
  const float* fc2w  = (const float*)d_in[12];
  const float* fc2b  = (const float*)d_in[13];
  float* out = (float*)d_out;

  char* ws  = (char*)d_ws;
  u16* bufA = (u16*)ws;                       // qkv 462MB -> h1 chunks
  u16* bufB = (u16*)(ws + 462422016L);        // xw -> attn_out -> xln2
  u16* wq   = (u16*)(ws + 616562688L);
  u16* wp   = wq + 110592;
  u16* w1   = wp + 36864;
  u16* w2   = w1 + 147456;
  float* bmt = (float*)d_out;   // 98304 floats, consumed by attn before proj

  convw<<<1728, 256, 0, stream>>>(qkvw, projw, fc1w, fc2w, wq);
  bmt_k<<<384, 256, 0, stream>>>(rpb, bmt);

  // LN1 + shift + window partition
  ln_kern<true><<<25088, 256, 0, stream>>>(x, n1g, n1b, bufB);
  // qkv (M=401408, N=576, K=192) -> permuted q,k,v.  grid = 3136*9 swizzled
  gemm_bt<0><<<3136*9, 512, 0, stream>>>(bufB, 192, 0, wq, 192, 192, 9,
                                         qkvb, bufA, nullptr, nullptr, 0);
  // windowed attention
  attn_k<<<12288, 256, 0, stream>>>(bufA, bmt, bufB);
  // proj (N=192) + scatter + residual -> d_out
  gemm_bt<1><<<3136*3, 512, 0, stream>>>(bufB, 192, 0, wp, 192, 192, 3,
                                         projb, nullptr, out, x, 0);
  // LN2
  ln_kern<false><<<25088, 256, 0, stream>>>(out, n2g, n2b, bufB);
  // MLP in 2 token-chunks (h1 chunk reuses bufA)
  for (int c = 0; c < 2; ++c){
    int off = c * 200704;
    gemm_bt<2><<<1568*12, 512, 0, stream>>>(bufB, 192, off, w1, 192, 192, 12,
                                            fc1b, bufA, nullptr, nullptr, 0);
    gemm_bt<3><<<1568*3, 512, 0, stream>>>(bufA, 768, 0, w2, 768, 768, 3,
                                           fc2b, nullptr, out, nullptr, off);
  }
}